// Round 2
// baseline (1538.316 us; speedup 1.0000x reference)
//
#include <hip/hip_runtime.h>

// FermiNet layer, fp32. B=4096 walkers, N=16 electrons (8 up), D1=256, D2=32, FLEN=832.
// d_in: single_h(B,N,D1) double_h(B,N,N,D2) v(N,FLEN,D1) b(N,D1) w(N,N,D2,D2) c(N,N,D2) n_up
// d_out: single_out (B*N*D1) ++ double_out (B*N*N*D2), fp32.

#define NWALK 4096
#define NEL   16
#define D1V   256
#define D2V   32

__device__ __forceinline__ float tanh_fast(float x) {
  // 1 - 2/(e^{2x}+1); exact limits at +-inf, ~1e-6 abs error via v_exp_f32
  return 1.0f - 2.0f / (__expf(2.0f * x) + 1.0f);
}

// ---------------- K1a: spin-resolved single pools g_up/g_dn (B,256) ----------------
__global__ __launch_bounds__(256) void k_pool_g(const float* __restrict__ sh,
                                                float* __restrict__ gup,
                                                float* __restrict__ gdn) {
  int idx = blockIdx.x * 256 + threadIdx.x;   // B*D1 = 1,048,576 threads
  int b = idx >> 8;
  int d = idx & 255;
  const float* p = sh + (size_t)b * (NEL * D1V) + d;
  float su = 0.f, sd = 0.f;
#pragma unroll
  for (int n = 0; n < 8; ++n) su += p[n * D1V];
#pragma unroll
  for (int n = 8; n < 16; ++n) sd += p[n * D1V];
  gup[idx] = su * 0.125f;
  gdn[idx] = sd * 0.125f;
}

// ---------------- K1b: double pools dg_up/dg_dn (B,N,32) ----------------
__global__ __launch_bounds__(256) void k_pool_dg(const float* __restrict__ dh,
                                                 float* __restrict__ dgup,
                                                 float* __restrict__ dgdn) {
  int idx = blockIdx.x * 256 + threadIdx.x;   // B*N*D2 = 2,097,152 threads
  int b = idx >> 9;
  int r = idx & 511;                          // i*32 + e
  const float* p = dh + (size_t)b * 8192 + (size_t)(r >> 5) * 512 + (r & 31);
  float su = 0.f, sd = 0.f;
#pragma unroll
  for (int j = 0; j < 8; ++j) su += p[j * 32];
#pragma unroll
  for (int j = 8; j < 16; ++j) sd += p[j * 32];
  dgup[idx] = su * 0.125f;
  dgdn[idx] = sd * 0.125f;
}

// ---------------- K2: single-stream GEMM ----------------
// Per n: C[b,o] = sum_f A[b,f] * v[n,f,o], f assembled on the fly from 5 segments.
// Block: 256 thr, BM=128 x BN=256 x BK=32; per-thread 8 rows x 16 cols (0.75 B LDS/FMA).
// grid.x = 16*32 = 512 = exactly 2 blocks/CU. n = bid>>5 so neighbors share V (L2-hot).
__device__ __forceinline__ void gload_lds16(const float* g, void* l) {
  __builtin_amdgcn_global_load_lds(
      (const __attribute__((address_space(1))) void*)g,
      (__attribute__((address_space(3))) void*)l, 16, 0, 0);
}

__global__ __launch_bounds__(256, 2) void k_single(
    const float* __restrict__ sh, const float* __restrict__ v,
    const float* __restrict__ bvec, const float* __restrict__ gup,
    const float* __restrict__ gdn, const float* __restrict__ dgup,
    const float* __restrict__ dgdn, float* __restrict__ out) {
  __shared__ float As[32 * 128];    // [k][row], 16 KB
  __shared__ float Vs[32 * 256];    // [k][col], 32 KB
  const int t = threadIdx.x;
  const int bid = blockIdx.x;
  const int n = bid >> 5;
  const int b0 = (bid & 31) * 128;
  const int tc = t & 15;            // cols tc*4 + 64*j, j=0..3
  const int tr = t >> 4;            // rows tr*8 .. tr*8+7
  const int wave = t >> 6;

  // A staging: rows ar0 + p*32 (p=0..3), one float4 of k each
  const int ar0 = t >> 3;           // 0..31
  const int akof = (t & 7) * 4;     // k offset 0,4,..,28

  float4 acc[4][8];                 // [colgrp j][row r]
#pragma unroll
  for (int j = 0; j < 4; ++j)
#pragma unroll
    for (int r = 0; r < 8; ++r) acc[j][r] = make_float4(0.f, 0.f, 0.f, 0.f);

  const float4* As4 = (const float4*)As;
  const float4* Vs4 = (const float4*)Vs;

  for (int kt = 0; kt < 26; ++kt) {
    // ---- select f-vector segment for this k-tile (uniform per block) ----
    const float* abase;
    int rstride;
    if (kt < 8)        { abase = sh   + (size_t)b0 * 4096 + n * 256 + kt * 32;  rstride = 4096; }
    else if (kt < 16)  { abase = gup  + (size_t)b0 * 256 + (kt - 8) * 32;       rstride = 256;  }
    else if (kt < 24)  { abase = gdn  + (size_t)b0 * 256 + (kt - 16) * 32;      rstride = 256;  }
    else if (kt == 24) { abase = dgup + (size_t)b0 * 512 + n * 32;              rstride = 512;  }
    else               { abase = dgdn + (size_t)b0 * 512 + n * 32;              rstride = 512;  }

    // ---- stage V tile (32x256) via global_load_lds, linear dest ----
    const float* vsrc = v + ((size_t)n * 832 + (size_t)kt * 32) * 256;
#pragma unroll
    for (int i = 0; i < 8; ++i) {
      gload_lds16(vsrc + 4 * (t + i * 256),
                  (char*)Vs + wave * 1024 + i * 4096);
    }

    // ---- stage A tile (128x32) transposed to [k][row] ----
#pragma unroll
    for (int p = 0; p < 4; ++p) {
      float4 a = *(const float4*)(abase + (size_t)(ar0 + p * 32) * rstride + akof);
      As[(akof + 0) * 128 + ar0 + p * 32] = a.x;
      As[(akof + 1) * 128 + ar0 + p * 32] = a.y;
      As[(akof + 2) * 128 + ar0 + p * 32] = a.z;
      As[(akof + 3) * 128 + ar0 + p * 32] = a.w;
    }

    __syncthreads();

#pragma unroll 2
    for (int k = 0; k < 32; ++k) {
      float4 a0 = As4[k * 32 + tr * 2];       // rows tr*8..+3 (broadcast across tc)
      float4 a1 = As4[k * 32 + tr * 2 + 1];   // rows tr*8+4..+7
      float4 vv[4];
      vv[0] = Vs4[k * 64 + tc];
      vv[1] = Vs4[k * 64 + tc + 16];
      vv[2] = Vs4[k * 64 + tc + 32];
      vv[3] = Vs4[k * 64 + tc + 48];
      float ar[8] = {a0.x, a0.y, a0.z, a0.w, a1.x, a1.y, a1.z, a1.w};
#pragma unroll
      for (int r = 0; r < 8; ++r)
#pragma unroll
        for (int j = 0; j < 4; ++j) {
          acc[j][r].x += ar[r] * vv[j].x;
          acc[j][r].y += ar[r] * vv[j].y;
          acc[j][r].z += ar[r] * vv[j].z;
          acc[j][r].w += ar[r] * vv[j].w;
        }
    }
    __syncthreads();
  }

  // ---- epilogue: bias + tanh + residual ----
#pragma unroll
  for (int r = 0; r < 8; ++r) {
    int b = b0 + tr * 8 + r;
    size_t rowbase = ((size_t)b * 16 + n) * 256;
#pragma unroll
    for (int j = 0; j < 4; ++j) {
      int col = j * 64 + tc * 4;
      float4 res = acc[j][r];
      float4 bias = *(const float4*)(bvec + n * 256 + col);
      float4 shv = *(const float4*)(sh + rowbase + col);
      float4 o;
      o.x = tanh_fast(res.x + bias.x) + shv.x;
      o.y = tanh_fast(res.y + bias.y) + shv.y;
      o.z = tanh_fast(res.z + bias.z) + shv.z;
      o.w = tanh_fast(res.w + bias.w) + shv.w;
      *(float4*)(out + rowbase + col) = o;
    }
  }
}

// ---------------- K3: double stream ----------------
// out[b,i,j,d] = tanh(sum_e w[i,j,d,e]*h[b,i,j,e] + c[i,j,d]) + h[b,i,j,d]
// Thread owns d-pair {2g,2g+1}: w rows in regs (64 f), h row via 8 float4 loads
// (16 same-addr lanes merge). No LDS, no shuffles, no barriers -> memory-bound.
__global__ __launch_bounds__(256) void k_double(const float* __restrict__ dh,
                                                const float* __restrict__ w,
                                                const float* __restrict__ c,
                                                float* __restrict__ out) {
  const int bid = blockIdx.x;       // 4096 = 256 pairs x 16 b-tiles
  const int pair = bid >> 4;        // consecutive blocks share pair -> w L2-hot
  const int b0 = (bid & 15) * 256;
  const int t = threadIdx.x;
  const int g = t & 15;             // d-pair: d = 2g, 2g+1
  const int slot = t >> 4;          // 0..15 walker slot

  float4 w0[8], w1[8];
  const float4* wp0 = (const float4*)(w + (size_t)pair * 1024 + (2 * g) * 32);
#pragma unroll
  for (int q = 0; q < 8; ++q) { w0[q] = wp0[q]; w1[q] = wp0[q + 8]; }
  const float2 cc = *(const float2*)(c + pair * 32 + 2 * g);

  for (int it = 0; it < 16; ++it) {
    int b = b0 + it * 16 + slot;
    const float4* hp = (const float4*)(dh + (size_t)b * 8192 + (size_t)pair * 32);
    float4 h4[8];
#pragma unroll
    for (int q = 0; q < 8; ++q) h4[q] = hp[q];
    float a0 = 0.f, a1 = 0.f;
#pragma unroll
    for (int q = 0; q < 8; ++q) {
      a0 += w0[q].x * h4[q].x + w0[q].y * h4[q].y + w0[q].z * h4[q].z + w0[q].w * h4[q].w;
      a1 += w1[q].x * h4[q].x + w1[q].y * h4[q].y + w1[q].z * h4[q].z + w1[q].w * h4[q].w;
    }
    float h0 = (g & 1) ? h4[g >> 1].z : h4[g >> 1].x;
    float h1 = (g & 1) ? h4[g >> 1].w : h4[g >> 1].y;
    float2 o;
    o.x = tanh_fast(a0 + cc.x) + h0;
    o.y = tanh_fast(a1 + cc.y) + h1;
    *(float2*)(out + (size_t)b * 8192 + (size_t)pair * 32 + 2 * g) = o;
  }
}

extern "C" void kernel_launch(void* const* d_in, const int* in_sizes, int n_in,
                              void* d_out, int out_size, void* d_ws, size_t ws_size,
                              hipStream_t stream) {
  const float* sh = (const float*)d_in[0];
  const float* dh = (const float*)d_in[1];
  const float* v  = (const float*)d_in[2];
  const float* bv = (const float*)d_in[3];
  const float* w  = (const float*)d_in[4];
  const float* c  = (const float*)d_in[5];
  float* out = (float*)d_out;
  float* ws = (float*)d_ws;

  float* gup  = ws;                 // B*256
  float* gdn  = ws + 1048576;       // B*256
  float* dgup = ws + 2097152;       // B*N*32
  float* dgdn = ws + 4194304;       // total ws: 24 MB
  float* out_s = out;               // (B,N,256)
  float* out_d = out + 16777216;    // (B,N,N,32)

  k_pool_g <<<4096, 256, 0, stream>>>(sh, gup, gdn);
  k_pool_dg<<<8192, 256, 0, stream>>>(dh, dgup, dgdn);
  k_single <<< 512, 256, 0, stream>>>(sh, v, bv, gup, gdn, dgup, dgdn, out_s);
  k_double <<<4096, 256, 0, stream>>>(dh, w, c, out_d);
}

// Round 5
// 811.380 us; speedup vs baseline: 1.8959x; 1.8959x over previous
//
#include <hip/hip_runtime.h>

// FermiNet layer, fp32. B=4096 walkers, N=16 electrons (8 up), D1=256, D2=32, FLEN=832.
// d_in: single_h(B,N,D1) double_h(B,N,N,D2) v(N,FLEN,D1) b(N,D1) w(N,N,D2,D2) c(N,N,D2) n_up
// d_out: single_out (B*N*D1) ++ double_out (B*N*N*D2), fp32.
//
// NOTE: no d_ws usage. Pool scratch lives at the START of the double-out region of
// d_out (24 MB of its 128 MB); k_single consumes it, then k_double (launched last,
// stream-ordered) overwrites the entire region with the final double_out values.
// This removes any assumption about ws_size (suspected cause of the R3 post-timing
// corruption: OOB scratch writes clobbering the harness's pristine input copies).

#define NWALK 4096
#define NEL   16
#define D1V   256
#define D2V   32

__device__ __forceinline__ float tanh_fast(float x) {
  // 1 - 2/(e^{2x}+1); exact limits at +-inf, ~1e-6 abs error via v_exp_f32
  return 1.0f - 2.0f / (__expf(2.0f * x) + 1.0f);
}

// ---------------- K1a: spin-resolved single pools g_up/g_dn (B,256) ----------------
__global__ __launch_bounds__(256) void k_pool_g(const float* __restrict__ sh,
                                                float* __restrict__ gup,
                                                float* __restrict__ gdn) {
  int idx = blockIdx.x * 256 + threadIdx.x;   // B*D1 = 1,048,576 threads
  int b = idx >> 8;
  int d = idx & 255;
  const float* p = sh + (size_t)b * (NEL * D1V) + d;
  float su = 0.f, sd = 0.f;
#pragma unroll
  for (int n = 0; n < 8; ++n) su += p[n * D1V];
#pragma unroll
  for (int n = 8; n < 16; ++n) sd += p[n * D1V];
  gup[idx] = su * 0.125f;
  gdn[idx] = sd * 0.125f;
}

// ---------------- K1b: double pools dg_up/dg_dn (B,N,32) ----------------
__global__ __launch_bounds__(256) void k_pool_dg(const float* __restrict__ dh,
                                                 float* __restrict__ dgup,
                                                 float* __restrict__ dgdn) {
  int idx = blockIdx.x * 256 + threadIdx.x;   // B*N*D2 = 2,097,152 threads
  int b = idx >> 9;
  int r = idx & 511;                          // i*32 + e
  const float* p = dh + (size_t)b * 8192 + (size_t)(r >> 5) * 512 + (r & 31);
  float su = 0.f, sd = 0.f;
#pragma unroll
  for (int j = 0; j < 8; ++j) su += p[j * 32];
#pragma unroll
  for (int j = 8; j < 16; ++j) sd += p[j * 32];
  dgup[idx] = su * 0.125f;
  dgdn[idx] = sd * 0.125f;
}

// ---------------- K2: single-stream GEMM ----------------
// Per n: C[b,o] = sum_f A[b,f] * v[n,f,o], f assembled on the fly from 5 segments.
// Block: 256 thr, BM=128 x BN=256 x BK=32; per-thread 8 rows x 16 cols (0.75 B LDS/FMA).
// grid.x = 16*32 = 512 = exactly 2 blocks/CU. n = bid>>5 so neighbors share V (L2-hot).
#define AS_STRIDE 132   // 128 + 4 pad: A-staging store conflicts 8-way -> 4-way,
                        // keeps row base 16B-aligned for float4 reads (132 % 4 == 0)

__device__ __forceinline__ void gload_lds16(const float* g, void* l) {
  __builtin_amdgcn_global_load_lds(
      (const __attribute__((address_space(1))) void*)g,
      (__attribute__((address_space(3))) void*)l, 16, 0, 0);
}

__global__ __launch_bounds__(256, 2) void k_single(
    const float* __restrict__ sh, const float* __restrict__ v,
    const float* __restrict__ bvec, const float* __restrict__ gup,
    const float* __restrict__ gdn, const float* __restrict__ dgup,
    const float* __restrict__ dgdn, float* __restrict__ out) {
  __shared__ float As[32 * AS_STRIDE];  // [k][row], 16.9 KB
  __shared__ float Vs[32 * 256];        // [k][col], 32 KB
  const int t = threadIdx.x;
  const int bid = blockIdx.x;
  const int n = bid >> 5;
  const int b0 = (bid & 31) * 128;
  const int tc = t & 15;            // cols tc*4 + 64*j, j=0..3
  const int tr = t >> 4;            // rows tr*8 .. tr*8+7
  const int wave = t >> 6;

  // A staging: rows ar0 + p*32 (p=0..3), one float4 of k each
  const int ar0 = t >> 3;           // 0..31
  const int akof = (t & 7) * 4;     // k offset 0,4,..,28

  float4 acc[4][8];                 // [colgrp j][row r]
#pragma unroll
  for (int j = 0; j < 4; ++j)
#pragma unroll
    for (int r = 0; r < 8; ++r) acc[j][r] = make_float4(0.f, 0.f, 0.f, 0.f);

  const float4* As4 = (const float4*)As;
  const float4* Vs4 = (const float4*)Vs;

  for (int kt = 0; kt < 26; ++kt) {
    // ---- select f-vector segment for this k-tile (uniform per block) ----
    const float* abase;
    int rstride;
    if (kt < 8)        { abase = sh   + (size_t)b0 * 4096 + n * 256 + kt * 32;  rstride = 4096; }
    else if (kt < 16)  { abase = gup  + (size_t)b0 * 256 + (kt - 8) * 32;       rstride = 256;  }
    else if (kt < 24)  { abase = gdn  + (size_t)b0 * 256 + (kt - 16) * 32;      rstride = 256;  }
    else if (kt == 24) { abase = dgup + (size_t)b0 * 512 + n * 32;              rstride = 512;  }
    else               { abase = dgdn + (size_t)b0 * 512 + n * 32;              rstride = 512;  }

    // ---- stage V tile (32x256) via global_load_lds, linear dest ----
    const float* vsrc = v + ((size_t)n * 832 + (size_t)kt * 32) * 256;
#pragma unroll
    for (int i = 0; i < 8; ++i) {
      gload_lds16(vsrc + 4 * (t + i * 256),
                  (char*)Vs + wave * 1024 + i * 4096);
    }

    // ---- stage A tile (128x32) transposed to [k][row] ----
#pragma unroll
    for (int p = 0; p < 4; ++p) {
      float4 a = *(const float4*)(abase + (size_t)(ar0 + p * 32) * rstride + akof);
      As[(akof + 0) * AS_STRIDE + ar0 + p * 32] = a.x;
      As[(akof + 1) * AS_STRIDE + ar0 + p * 32] = a.y;
      As[(akof + 2) * AS_STRIDE + ar0 + p * 32] = a.z;
      As[(akof + 3) * AS_STRIDE + ar0 + p * 32] = a.w;
    }

    __syncthreads();

#pragma unroll 2
    for (int k = 0; k < 32; ++k) {
      float4 a0 = As4[k * (AS_STRIDE / 4) + tr * 2];       // rows tr*8..+3
      float4 a1 = As4[k * (AS_STRIDE / 4) + tr * 2 + 1];   // rows tr*8+4..+7
      float4 vv[4];
      vv[0] = Vs4[k * 64 + tc];
      vv[1] = Vs4[k * 64 + tc + 16];
      vv[2] = Vs4[k * 64 + tc + 32];
      vv[3] = Vs4[k * 64 + tc + 48];
      float ar[8] = {a0.x, a0.y, a0.z, a0.w, a1.x, a1.y, a1.z, a1.w};
#pragma unroll
      for (int r = 0; r < 8; ++r)
#pragma unroll
        for (int j = 0; j < 4; ++j) {
          acc[j][r].x += ar[r] * vv[j].x;
          acc[j][r].y += ar[r] * vv[j].y;
          acc[j][r].z += ar[r] * vv[j].z;
          acc[j][r].w += ar[r] * vv[j].w;
        }
    }
    __syncthreads();
  }

  // ---- epilogue: bias + tanh + residual ----
#pragma unroll
  for (int r = 0; r < 8; ++r) {
    int b = b0 + tr * 8 + r;
    size_t rowbase = ((size_t)b * 16 + n) * 256;
#pragma unroll
    for (int j = 0; j < 4; ++j) {
      int col = j * 64 + tc * 4;
      float4 res = acc[j][r];
      float4 bias = *(const float4*)(bvec + n * 256 + col);
      float4 shv = *(const float4*)(sh + rowbase + col);
      float4 o;
      o.x = tanh_fast(res.x + bias.x) + shv.x;
      o.y = tanh_fast(res.y + bias.y) + shv.y;
      o.z = tanh_fast(res.z + bias.z) + shv.z;
      o.w = tanh_fast(res.w + bias.w) + shv.w;
      *(float4*)(out + rowbase + col) = o;
    }
  }
}

// ---------------- K3: double stream ----------------
// out[b,i,j,d] = tanh(sum_e w[i,j,d,e]*h[b,i,j,e] + c[i,j,d]) + h[b,i,j,d]
// Thread owns d-pair {2g,2g+1}: w rows in regs (64 f, statically indexed only),
// h row via 8 float4 loads kept as SCALARS (rule #20: no runtime-indexed arrays!),
// residual re-loaded as float2 (L1-hot line). No LDS, no shuffles, no barriers.
// Runs LAST: overwrites the entire double-out region, including the pool scratch.
__global__ __launch_bounds__(256) void k_double(const float* __restrict__ dh,
                                                const float* __restrict__ w,
                                                const float* __restrict__ c,
                                                float* __restrict__ out) {
  const int bid = blockIdx.x;       // 4096 = 256 pairs x 16 b-tiles
  const int pair = bid >> 4;        // consecutive blocks share pair -> w L2-hot
  const int b0 = (bid & 15) * 256;
  const int t = threadIdx.x;
  const int g = t & 15;             // d-pair: d = 2g, 2g+1
  const int slot = t >> 4;          // 0..15 walker slot

  float4 w0[8], w1[8];
  const float4* wp0 = (const float4*)(w + (size_t)pair * 1024 + (2 * g) * 32);
#pragma unroll
  for (int q = 0; q < 8; ++q) { w0[q] = wp0[q]; w1[q] = wp0[q + 8]; }
  const float2 cc = *(const float2*)(c + pair * 32 + 2 * g);

  for (int it = 0; it < 16; ++it) {
    int b = b0 + it * 16 + slot;
    const size_t rowoff = (size_t)b * 8192 + (size_t)pair * 32;
    const float4* hp = (const float4*)(dh + rowoff);
    float a0 = 0.f, a1 = 0.f;
#pragma unroll
    for (int q = 0; q < 8; ++q) {
      float4 h4 = hp[q];            // scalar float4, never array-indexed
      a0 += w0[q].x * h4.x + w0[q].y * h4.y + w0[q].z * h4.z + w0[q].w * h4.w;
      a1 += w1[q].x * h4.x + w1[q].y * h4.y + w1[q].z * h4.z + w1[q].w * h4.w;
    }
    float2 hres = *(const float2*)(dh + rowoff + 2 * g);   // L1-hot
    float2 o;
    o.x = tanh_fast(a0 + cc.x) + hres.x;
    o.y = tanh_fast(a1 + cc.y) + hres.y;
    *(float2*)(out + rowoff + 2 * g) = o;
  }
}

extern "C" void kernel_launch(void* const* d_in, const int* in_sizes, int n_in,
                              void* d_out, int out_size, void* d_ws, size_t ws_size,
                              hipStream_t stream) {
  const float* sh = (const float*)d_in[0];
  const float* dh = (const float*)d_in[1];
  const float* v  = (const float*)d_in[2];
  const float* bv = (const float*)d_in[3];
  const float* w  = (const float*)d_in[4];
  const float* c  = (const float*)d_in[5];
  float* out = (float*)d_out;
  (void)d_ws; (void)ws_size;        // d_ws unused: size not auditable

  float* out_s = out;               // (B,N,256)   = 16,777,216 floats
  float* out_d = out + 16777216;    // (B,N,N,32)  = 33,554,432 floats

  // Pool scratch inside the double-out region (k_double overwrites it last):
  float* gup  = out_d;              // 1,048,576 f
  float* gdn  = out_d + 1048576;    // 1,048,576 f
  float* dgup = out_d + 2097152;    // 2,097,152 f
  float* dgdn = out_d + 4194304;    // 2,097,152 f  (total 24 MB < 128 MB region)

  k_pool_g <<<4096, 256, 0, stream>>>(sh, gup, gdn);
  k_pool_dg<<<8192, 256, 0, stream>>>(dh, dgup, dgdn);
  k_single <<< 512, 256, 0, stream>>>(sh, v, bv, gup, gdn, dgup, dgdn, out_s);
  k_double <<<4096, 256, 0, stream>>>(dh, w, c, out_d);
}

// Round 7
// 616.238 us; speedup vs baseline: 2.4963x; 1.3167x over previous
//
#include <hip/hip_runtime.h>

// FermiNet layer, fp32 in/out. B=4096, N=16 (8 up), D1=256, D2=32, FLEN=832.
// d_out: single_out (B*N*256) ++ double_out (B*N*N*32), fp32.
//
// R7 == R6 + alignas(16) on LDS arrays (desk-check hardening; bf16x8 casts).
// k_single: 3-term bf16-split MFMA GEMM (Ah*Vh + Al*Vh + Ah*Vl, fp32 accum).
// V pre-split into bf16 hi/lo, transposed to [col][k] and PRE-SWIZZLED in
// global by k_vsplit so linear global_load_lds lands the swizzled LDS image
// (rule #21: swizzle both sides or neither). Scratch lives inside the
// double-out region of d_out; k_double runs last and overwrites it (R3 fix).

#define NWALK 4096
#define NEL   16
#define D1V   256
#define D2V   32

typedef short  bf16x8 __attribute__((ext_vector_type(8)));   // 8 bf16 (4 VGPR)
typedef float  f32x4  __attribute__((ext_vector_type(4)));
typedef unsigned short u16;

__device__ __forceinline__ float tanh_fast(float x) {
  return 1.0f - 2.0f / (__expf(2.0f * x) + 1.0f);
}
__device__ __forceinline__ u16 bf16_rne(float f) {
  unsigned u = __float_as_uint(f);
  unsigned r = (u + 0x7FFFu + ((u >> 16) & 1u)) >> 16;
  return (u16)r;
}
__device__ __forceinline__ float bf16_to_f(u16 h) {
  return __uint_as_float(((unsigned)h) << 16);
}
__device__ __forceinline__ void gload_lds16(const void* g, void* l) {
  __builtin_amdgcn_global_load_lds(
      (const __attribute__((address_space(1))) void*)g,
      (__attribute__((address_space(3))) void*)l, 16, 0, 0);
}

// ---------------- K1a: spin pools g_up/g_dn (B,256) ----------------
__global__ __launch_bounds__(256) void k_pool_g(const float* __restrict__ sh,
                                                float* __restrict__ gup,
                                                float* __restrict__ gdn) {
  int idx = blockIdx.x * 256 + threadIdx.x;
  int b = idx >> 8;
  int d = idx & 255;
  const float* p = sh + (size_t)b * (NEL * D1V) + d;
  float su = 0.f, sd = 0.f;
#pragma unroll
  for (int n = 0; n < 8; ++n) su += p[n * D1V];
#pragma unroll
  for (int n = 8; n < 16; ++n) sd += p[n * D1V];
  gup[idx] = su * 0.125f;
  gdn[idx] = sd * 0.125f;
}

// ---------------- K1b: double pools dg_up/dg_dn (B,N,32) ----------------
__global__ __launch_bounds__(256) void k_pool_dg(const float* __restrict__ dh,
                                                 float* __restrict__ dgup,
                                                 float* __restrict__ dgdn) {
  int idx = blockIdx.x * 256 + threadIdx.x;
  int b = idx >> 9;
  int r = idx & 511;
  const float* p = dh + (size_t)b * 8192 + (size_t)(r >> 5) * 512 + (r & 31);
  float su = 0.f, sd = 0.f;
#pragma unroll
  for (int j = 0; j < 8; ++j) su += p[j * 32];
#pragma unroll
  for (int j = 8; j < 16; ++j) sd += p[j * 32];
  dgup[idx] = su * 0.125f;
  dgdn[idx] = sd * 0.125f;
}

// ---------------- K1c: V split+transpose+swizzle ----------------
// vsplit[(n*26+kt)] = 32KB block: hi image (8192 u16) ++ lo image (8192 u16).
// Granule slot cp (16B = 8 u16) at col*32 + cp*8 holds k-chunk ks = cp ^ sw,
// sw=(col>>1)&3: value V[kt*32 + ks*8 + j][col]. Linear gload_lds reproduces
// this image in LDS byte-for-byte.
__global__ __launch_bounds__(256) void k_vsplit(const float* __restrict__ v,
                                                u16* __restrict__ vs) {
  int nb = blockIdx.x;               // n*26 + kt
  int n = nb / 26, kt = nb - n * 26;
  int col = threadIdx.x;
  const float* src = v + ((size_t)n * 832 + (size_t)kt * 32) * 256 + col;
  u16* hb = vs + (size_t)nb * 16384;
  u16* lb = hb + 8192;
  int sw = (col >> 1) & 3;
#pragma unroll
  for (int cp = 0; cp < 4; ++cp) {
    int ks = cp ^ sw;
    bf16x8 hi, lo;
#pragma unroll
    for (int j = 0; j < 8; ++j) {
      float f = src[(size_t)(ks * 8 + j) * 256];
      u16 h = bf16_rne(f);
      hi[j] = (short)h;
      lo[j] = (short)bf16_rne(f - bf16_to_f(h));
    }
    *(bf16x8*)(hb + col * 32 + cp * 8) = hi;
    *(bf16x8*)(lb + col * 32 + cp * 8) = lo;
  }
}

// ---------------- K2: single-stream GEMM via bf16-split MFMA ----------------
// Per n: C[b,o] = sum_f A[b,f]*V[f][o]; A assembled from 5 segments on the fly.
// Block 256 thr / 4 waves (2x2), BM=128 BN=256 BK=32; per-wave 4x8 frags of
// mfma_f32_16x16x32_bf16, 3 terms. LDS 48KB, 2 blk/CU.
// Frag layout (gfx950): A lane l: row=l&15, k=(l>>4)*8+j ; B: col=l&15, same k
// (any consistent k-permutation cancels between A and B); D: row=(l>>4)*4+j,
// col=l&15 (m89-verified).
__global__ __launch_bounds__(256, 2) void k_single(
    const float* __restrict__ sh, const u16* __restrict__ vs,
    const float* __restrict__ bvec, const float* __restrict__ gup,
    const float* __restrict__ gdn, const float* __restrict__ dgup,
    const float* __restrict__ dgdn, float* __restrict__ out) {
  __shared__ alignas(16) short A2[2][128][32];   // [hi/lo][row][k-swz] 16KB
  __shared__ alignas(16) short V2[2][256][32];   // [hi/lo][col][k-swz] 32KB
  const int t = threadIdx.x;
  const int bid = blockIdx.x;
  const int n = bid >> 5;
  const int b0 = (bid & 31) * 128;
  const int lane = t & 63;
  const int w = t >> 6;
  const int wr = w >> 1, wc = w & 1;
  const int l15 = lane & 15, l4 = lane >> 4;

  // Loop-invariant LDS frag offsets (u16 units). Adding m*16 rows / nf*16 cols
  // (= 512 u16) leaves the swizzle term unchanged ((16>>1)&3 == 0 mod 4).
  const int arow = wr * 64 + l15;                    // + m*16
  const int aslot = l4 ^ ((arow >> 1) & 3);
  const int aoff = arow * 32 + aslot * 8;            // + m*512
  const int bcol = wc * 128 + l15;                   // + nf*16
  const int bslot = l4 ^ ((bcol >> 1) & 3);
  const int boff = bcol * 32 + bslot * 8;            // + nf*512

  // A staging: thread owns row srow, k-chunks sc0 and sc0+2 (8 fp32 each)
  const int srow = t & 127;
  const int sc0 = t >> 7;                            // 0..1
  const int sslot0 = sc0 ^ ((srow >> 1) & 3);
  const int sslot1 = (sc0 + 2) ^ ((srow >> 1) & 3);

  f32x4 acc[4][8];
#pragma unroll
  for (int m = 0; m < 4; ++m)
#pragma unroll
    for (int nf = 0; nf < 8; ++nf) acc[m][nf] = (f32x4){0.f, 0.f, 0.f, 0.f};

  const short* Ab = &A2[0][0][0];
  const short* Vb = &V2[0][0][0];

  for (int kt = 0; kt < 26; ++kt) {
    // ---- segment select (uniform per block) ----
    const float* abase;
    int rstride;
    if (kt < 8)        { abase = sh   + (size_t)b0 * 4096 + n * 256 + kt * 32;  rstride = 4096; }
    else if (kt < 16)  { abase = gup  + (size_t)b0 * 256 + (kt - 8) * 32;       rstride = 256;  }
    else if (kt < 24)  { abase = gdn  + (size_t)b0 * 256 + (kt - 16) * 32;      rstride = 256;  }
    else if (kt == 24) { abase = dgup + (size_t)b0 * 512 + n * 32;              rstride = 512;  }
    else               { abase = dgdn + (size_t)b0 * 512 + n * 32;              rstride = 512;  }

    // ---- stage V hi+lo (32KB) via linear gload_lds of pre-swizzled image ----
    const u16* vsrc = vs + (size_t)(n * 26 + kt) * 16384;
#pragma unroll
    for (int i = 0; i < 8; ++i) {
      gload_lds16(vsrc + (size_t)(i * 256 + t) * 8,
                  (char*)Vb + w * 1024 + i * 4096);
    }

    // ---- stage A: load 16 fp32, split, swizzled ds_write ----
    {
      const float* ap = abase + (size_t)srow * rstride;
      float4 x0 = *(const float4*)(ap + sc0 * 8);
      float4 x1 = *(const float4*)(ap + sc0 * 8 + 4);
      float4 y0 = *(const float4*)(ap + sc0 * 8 + 16);
      float4 y1 = *(const float4*)(ap + sc0 * 8 + 20);
      bf16x8 xh, xl, yh, yl;
      float xs[8] = {x0.x, x0.y, x0.z, x0.w, x1.x, x1.y, x1.z, x1.w};
      float ys[8] = {y0.x, y0.y, y0.z, y0.w, y1.x, y1.y, y1.z, y1.w};
#pragma unroll
      for (int j = 0; j < 8; ++j) {
        u16 h = bf16_rne(xs[j]);
        xh[j] = (short)h; xl[j] = (short)bf16_rne(xs[j] - bf16_to_f(h));
        u16 g = bf16_rne(ys[j]);
        yh[j] = (short)g; yl[j] = (short)bf16_rne(ys[j] - bf16_to_f(g));
      }
      *(bf16x8*)&A2[0][srow][sslot0 * 8] = xh;
      *(bf16x8*)&A2[1][srow][sslot0 * 8] = xl;
      *(bf16x8*)&A2[0][srow][sslot1 * 8] = yh;
      *(bf16x8*)&A2[1][srow][sslot1 * 8] = yl;
    }

    __syncthreads();

    // ---- MFMA: 96 per wave per k-step ----
    bf16x8 ah[4], al[4];
#pragma unroll
    for (int m = 0; m < 4; ++m) {
      ah[m] = *(const bf16x8*)(Ab + aoff + m * 512);          // A2[0]
      al[m] = *(const bf16x8*)(Ab + 4096 + aoff + m * 512);   // A2[1]
    }
#pragma unroll
    for (int nf = 0; nf < 8; ++nf) {
      bf16x8 bh = *(const bf16x8*)(Vb + boff + nf * 512);         // V2[0]
      bf16x8 bl = *(const bf16x8*)(Vb + 8192 + boff + nf * 512);  // V2[1]
#pragma unroll
      for (int m = 0; m < 4; ++m) {
        acc[m][nf] = __builtin_amdgcn_mfma_f32_16x16x32_bf16(ah[m], bh, acc[m][nf], 0, 0, 0);
        acc[m][nf] = __builtin_amdgcn_mfma_f32_16x16x32_bf16(al[m], bh, acc[m][nf], 0, 0, 0);
        acc[m][nf] = __builtin_amdgcn_mfma_f32_16x16x32_bf16(ah[m], bl, acc[m][nf], 0, 0, 0);
      }
    }
    __syncthreads();
  }

  // ---- epilogue: bias + tanh + residual ----
#pragma unroll
  for (int nf = 0; nf < 8; ++nf) {
    const int col = wc * 128 + nf * 16 + l15;
    const float bias_v = bvec[n * 256 + col];
#pragma unroll
    for (int m = 0; m < 4; ++m) {
      const int brow0 = b0 + wr * 64 + m * 16 + l4 * 4;
#pragma unroll
      for (int j = 0; j < 4; ++j) {
        const size_t idx = ((size_t)(brow0 + j) * 16 + n) * 256 + col;
        out[idx] = tanh_fast(acc[m][nf][j] + bias_v) + sh[idx];
      }
    }
  }
}

// ---------------- K3: double stream (unchanged, R5-verified) ----------------
__global__ __launch_bounds__(256) void k_double(const float* __restrict__ dh,
                                                const float* __restrict__ w,
                                                const float* __restrict__ c,
                                                float* __restrict__ out) {
  const int bid = blockIdx.x;
  const int pair = bid >> 4;
  const int b0 = (bid & 15) * 256;
  const int t = threadIdx.x;
  const int g = t & 15;
  const int slot = t >> 4;

  float4 w0[8], w1[8];
  const float4* wp0 = (const float4*)(w + (size_t)pair * 1024 + (2 * g) * 32);
#pragma unroll
  for (int q = 0; q < 8; ++q) { w0[q] = wp0[q]; w1[q] = wp0[q + 8]; }
  const float2 cc = *(const float2*)(c + pair * 32 + 2 * g);

  for (int it = 0; it < 16; ++it) {
    int b = b0 + it * 16 + slot;
    const size_t rowoff = (size_t)b * 8192 + (size_t)pair * 32;
    const float4* hp = (const float4*)(dh + rowoff);
    float a0 = 0.f, a1 = 0.f;
#pragma unroll
    for (int q = 0; q < 8; ++q) {
      float4 h4 = hp[q];
      a0 += w0[q].x * h4.x + w0[q].y * h4.y + w0[q].z * h4.z + w0[q].w * h4.w;
      a1 += w1[q].x * h4.x + w1[q].y * h4.y + w1[q].z * h4.z + w1[q].w * h4.w;
    }
    float2 hres = *(const float2*)(dh + rowoff + 2 * g);
    float2 o;
    o.x = tanh_fast(a0 + cc.x) + hres.x;
    o.y = tanh_fast(a1 + cc.y) + hres.y;
    *(float2*)(out + rowoff + 2 * g) = o;
  }
}

extern "C" void kernel_launch(void* const* d_in, const int* in_sizes, int n_in,
                              void* d_out, int out_size, void* d_ws, size_t ws_size,
                              hipStream_t stream) {
  const float* sh = (const float*)d_in[0];
  const float* dh = (const float*)d_in[1];
  const float* v  = (const float*)d_in[2];
  const float* bv = (const float*)d_in[3];
  const float* w  = (const float*)d_in[4];
  const float* c  = (const float*)d_in[5];
  float* out = (float*)d_out;
  (void)d_ws; (void)ws_size;

  float* out_s = out;               // (B,N,256)   = 16,777,216 f
  float* out_d = out + 16777216;    // (B,N,N,32)  = 33,554,432 f

  // Scratch inside double-out region (k_double overwrites it last):
  float* gup  = out_d;                       // 1,048,576 f
  float* gdn  = out_d + 1048576;             // 1,048,576 f
  float* dgup = out_d + 2097152;             // 2,097,152 f
  float* dgdn = out_d + 4194304;             // 2,097,152 f
  u16*  vspl  = (u16*)(out_d + 6291456);     // 16*26*16384 u16 = 13.6 MB

  k_pool_g <<<4096, 256, 0, stream>>>(sh, gup, gdn);
  k_pool_dg<<<8192, 256, 0, stream>>>(dh, dgup, dgdn);
  k_vsplit <<< 416, 256, 0, stream>>>(v, vspl);
  k_single <<< 512, 256, 0, stream>>>(sh, vspl, bv, gup, gdn, dgup, dgdn, out_s);
  k_double <<<4096, 256, 0, stream>>>(dh, w, c, out_d);
}

// Round 11
// 524.039 us; speedup vs baseline: 2.9355x; 1.1759x over previous
//
#include <hip/hip_runtime.h>

// FermiNet layer, fp32 in/out. B=4096, N=16 (8 up), D1=256, D2=32, FLEN=832.
// d_out: single_out (B*N*256) ++ double_out (B*N*N*32), fp32.
//
// R11 == R9/R10 (resubmit; infra failures, kernel never ran). k_double:
// LDS-staged h-tile (coalesced 128B segments; stride 36 -> all accesses
// <=2-way), d-quad per thread, w-rows static in regs (rule #20). k_single:
// 3-term bf16-split MFMA GEMM (R7-verified). Scratch inside double-out
// region; k_double overwrites it last (R3 corruption fix).

#define NWALK 4096
#define NEL   16
#define D1V   256
#define D2V   32

typedef short  bf16x8 __attribute__((ext_vector_type(8)));   // 8 bf16 (4 VGPR)
typedef float  f32x4  __attribute__((ext_vector_type(4)));
typedef unsigned short u16;

__device__ __forceinline__ float tanh_fast(float x) {
  return 1.0f - 2.0f / (__expf(2.0f * x) + 1.0f);
}
__device__ __forceinline__ u16 bf16_rne(float f) {
  unsigned u = __float_as_uint(f);
  unsigned r = (u + 0x7FFFu + ((u >> 16) & 1u)) >> 16;
  return (u16)r;
}
__device__ __forceinline__ float bf16_to_f(u16 h) {
  return __uint_as_float(((unsigned)h) << 16);
}
__device__ __forceinline__ void gload_lds16(const void* g, void* l) {
  __builtin_amdgcn_global_load_lds(
      (const __attribute__((address_space(1))) void*)g,
      (__attribute__((address_space(3))) void*)l, 16, 0, 0);
}

// ---------------- K1a: spin pools g_up/g_dn (B,256) ----------------
__global__ __launch_bounds__(256) void k_pool_g(const float* __restrict__ sh,
                                                float* __restrict__ gup,
                                                float* __restrict__ gdn) {
  int idx = blockIdx.x * 256 + threadIdx.x;
  int b = idx >> 8;
  int d = idx & 255;
  const float* p = sh + (size_t)b * (NEL * D1V) + d;
  float su = 0.f, sd = 0.f;
#pragma unroll
  for (int n = 0; n < 8; ++n) su += p[n * D1V];
#pragma unroll
  for (int n = 8; n < 16; ++n) sd += p[n * D1V];
  gup[idx] = su * 0.125f;
  gdn[idx] = sd * 0.125f;
}

// ---------------- K1b: double pools dg_up/dg_dn (B,N,32) ----------------
__global__ __launch_bounds__(256) void k_pool_dg(const float* __restrict__ dh,
                                                 float* __restrict__ dgup,
                                                 float* __restrict__ dgdn) {
  int idx = blockIdx.x * 256 + threadIdx.x;
  int b = idx >> 9;
  int r = idx & 511;
  const float* p = dh + (size_t)b * 8192 + (size_t)(r >> 5) * 512 + (r & 31);
  float su = 0.f, sd = 0.f;
#pragma unroll
  for (int j = 0; j < 8; ++j) su += p[j * 32];
#pragma unroll
  for (int j = 8; j < 16; ++j) sd += p[j * 32];
  dgup[idx] = su * 0.125f;
  dgdn[idx] = sd * 0.125f;
}

// ---------------- K1c: V split+transpose+swizzle (R7-verified) ----------------
__global__ __launch_bounds__(256) void k_vsplit(const float* __restrict__ v,
                                                u16* __restrict__ vs) {
  int nb = blockIdx.x;               // n*26 + kt
  int n = nb / 26, kt = nb - n * 26;
  int col = threadIdx.x;
  const float* src = v + ((size_t)n * 832 + (size_t)kt * 32) * 256 + col;
  u16* hb = vs + (size_t)nb * 16384;
  u16* lb = hb + 8192;
  int sw = (col >> 1) & 3;
#pragma unroll
  for (int cp = 0; cp < 4; ++cp) {
    int ks = cp ^ sw;
    bf16x8 hi, lo;
#pragma unroll
    for (int j = 0; j < 8; ++j) {
      float f = src[(size_t)(ks * 8 + j) * 256];
      u16 h = bf16_rne(f);
      hi[j] = (short)h;
      lo[j] = (short)bf16_rne(f - bf16_to_f(h));
    }
    *(bf16x8*)(hb + col * 32 + cp * 8) = hi;
    *(bf16x8*)(lb + col * 32 + cp * 8) = lo;
  }
}

// ---------------- K2: single-stream GEMM via bf16-split MFMA (R7-verified) ----------------
__global__ __launch_bounds__(256, 2) void k_single(
    const float* __restrict__ sh, const u16* __restrict__ vs,
    const float* __restrict__ bvec, const float* __restrict__ gup,
    const float* __restrict__ gdn, const float* __restrict__ dgup,
    const float* __restrict__ dgdn, float* __restrict__ out) {
  __shared__ alignas(16) short A2[2][128][32];   // [hi/lo][row][k-swz] 16KB
  __shared__ alignas(16) short V2[2][256][32];   // [hi/lo][col][k-swz] 32KB
  const int t = threadIdx.x;
  const int bid = blockIdx.x;
  const int n = bid >> 5;
  const int b0 = (bid & 31) * 128;
  const int lane = t & 63;
  const int w = t >> 6;
  const int wr = w >> 1, wc = w & 1;
  const int l15 = lane & 15, l4 = lane >> 4;

  const int arow = wr * 64 + l15;                    // + m*16
  const int aslot = l4 ^ ((arow >> 1) & 3);
  const int aoff = arow * 32 + aslot * 8;            // + m*512
  const int bcol = wc * 128 + l15;                   // + nf*16
  const int bslot = l4 ^ ((bcol >> 1) & 3);
  const int boff = bcol * 32 + bslot * 8;            // + nf*512

  const int srow = t & 127;
  const int sc0 = t >> 7;                            // 0..1
  const int sslot0 = sc0 ^ ((srow >> 1) & 3);
  const int sslot1 = (sc0 + 2) ^ ((srow >> 1) & 3);

  f32x4 acc[4][8];
#pragma unroll
  for (int m = 0; m < 4; ++m)
#pragma unroll
    for (int nf = 0; nf < 8; ++nf) acc[m][nf] = (f32x4){0.f, 0.f, 0.f, 0.f};

  const short* Ab = &A2[0][0][0];
  const short* Vb = &V2[0][0][0];

  for (int kt = 0; kt < 26; ++kt) {
    const float* abase;
    int rstride;
    if (kt < 8)        { abase = sh   + (size_t)b0 * 4096 + n * 256 + kt * 32;  rstride = 4096; }
    else if (kt < 16)  { abase = gup  + (size_t)b0 * 256 + (kt - 8) * 32;       rstride = 256;  }
    else if (kt < 24)  { abase = gdn  + (size_t)b0 * 256 + (kt - 16) * 32;      rstride = 256;  }
    else if (kt == 24) { abase = dgup + (size_t)b0 * 512 + n * 32;              rstride = 512;  }
    else               { abase = dgdn + (size_t)b0 * 512 + n * 32;              rstride = 512;  }

    const u16* vsrc = vs + (size_t)(n * 26 + kt) * 16384;
#pragma unroll
    for (int i = 0; i < 8; ++i) {
      gload_lds16(vsrc + (size_t)(i * 256 + t) * 8,
                  (char*)Vb + w * 1024 + i * 4096);
    }

    {
      const float* ap = abase + (size_t)srow * rstride;
      float4 x0 = *(const float4*)(ap + sc0 * 8);
      float4 x1 = *(const float4*)(ap + sc0 * 8 + 4);
      float4 y0 = *(const float4*)(ap + sc0 * 8 + 16);
      float4 y1 = *(const float4*)(ap + sc0 * 8 + 20);
      bf16x8 xh, xl, yh, yl;
      float xs[8] = {x0.x, x0.y, x0.z, x0.w, x1.x, x1.y, x1.z, x1.w};
      float ys[8] = {y0.x, y0.y, y0.z, y0.w, y1.x, y1.y, y1.z, y1.w};
#pragma unroll
      for (int j = 0; j < 8; ++j) {
        u16 h = bf16_rne(xs[j]);
        xh[j] = (short)h; xl[j] = (short)bf16_rne(xs[j] - bf16_to_f(h));
        u16 g = bf16_rne(ys[j]);
        yh[j] = (short)g; yl[j] = (short)bf16_rne(ys[j] - bf16_to_f(g));
      }
      *(bf16x8*)&A2[0][srow][sslot0 * 8] = xh;
      *(bf16x8*)&A2[1][srow][sslot0 * 8] = xl;
      *(bf16x8*)&A2[0][srow][sslot1 * 8] = yh;
      *(bf16x8*)&A2[1][srow][sslot1 * 8] = yl;
    }

    __syncthreads();

    bf16x8 ah[4], al[4];
#pragma unroll
    for (int m = 0; m < 4; ++m) {
      ah[m] = *(const bf16x8*)(Ab + aoff + m * 512);          // A2[0]
      al[m] = *(const bf16x8*)(Ab + 4096 + aoff + m * 512);   // A2[1]
    }
#pragma unroll
    for (int nf = 0; nf < 8; ++nf) {
      bf16x8 bh = *(const bf16x8*)(Vb + boff + nf * 512);         // V2[0]
      bf16x8 bl = *(const bf16x8*)(Vb + 8192 + boff + nf * 512);  // V2[1]
#pragma unroll
      for (int m = 0; m < 4; ++m) {
        acc[m][nf] = __builtin_amdgcn_mfma_f32_16x16x32_bf16(ah[m], bh, acc[m][nf], 0, 0, 0);
        acc[m][nf] = __builtin_amdgcn_mfma_f32_16x16x32_bf16(al[m], bh, acc[m][nf], 0, 0, 0);
        acc[m][nf] = __builtin_amdgcn_mfma_f32_16x16x32_bf16(ah[m], bl, acc[m][nf], 0, 0, 0);
      }
    }
    __syncthreads();
  }

#pragma unroll
  for (int nf = 0; nf < 8; ++nf) {
    const int col = wc * 128 + nf * 16 + l15;
    const float bias_v = bvec[n * 256 + col];
#pragma unroll
    for (int m = 0; m < 4; ++m) {
      const int brow0 = b0 + wr * 64 + m * 16 + l4 * 4;
#pragma unroll
      for (int j = 0; j < 4; ++j) {
        const size_t idx = ((size_t)(brow0 + j) * 16 + n) * 256 + col;
        out[idx] = tanh_fast(acc[m][nf][j] + bias_v) + sh[idx];
      }
    }
  }
}

// ---------------- K3: double stream, LDS-staged (R8 rewrite + alignas) ----------------
// out[b,i,j,d] = tanh(sum_e w[i,j,d,e]*h[b,i,j,e] + c[i,j,d]) + h[b,i,j,d]
// Block = (pair, 256-row b-tile). Stage h-tile into LDS with fully-coalesced
// 128B-segment loads; pad row stride to 36 words -> all LDS phases <=2-way.
// Thread owns d-QUAD d=g*4..g*4+3: w-rows (128 f) in regs, statically indexed
// (rule #20); dot reads h row from LDS (8-lane broadcast). Stores coalesced
// float4. FP order identical to R5/R7 k_double -> absmax unchanged.
__global__ __launch_bounds__(256, 2) void k_double(const float* __restrict__ dh,
                                                   const float* __restrict__ w,
                                                   const float* __restrict__ c,
                                                   float* __restrict__ out) {
  __shared__ alignas(16) float h_lds[256][36];   // 36.9 KB
  const int bid = blockIdx.x;        // 4096 = 256 pairs x 16 b-tiles
  const int pair = bid >> 4;         // consecutive blocks share pair -> w L2-hot
  const int b0 = (bid & 15) * 256;
  const int t = threadIdx.x;
  const int g = t & 7;               // d-quad index: d = g*4 .. g*4+3
  const int s = t >> 3;              // row-slot 0..31

  // ---- w rows into regs: 4 d-rows x 32 e = 128 f (all indices static) ----
  float4 wr[4][8];
  {
    const float4* wp = (const float4*)(w + (size_t)pair * 1024 + (size_t)(g * 4) * 32);
#pragma unroll
    for (int d = 0; d < 4; ++d)
#pragma unroll
      for (int q = 0; q < 8; ++q) wr[d][q] = wp[d * 8 + q];
  }
  const float4 cc = *(const float4*)(c + pair * 32 + g * 4);

  // ---- stage h tile (256 rows x 32 f), coalesced: 8 rows x 128B per instr ----
  {
    const int q = t & 7;             // quad within row
#pragma unroll
    for (int p = 0; p < 8; ++p) {
      const int r = p * 32 + s;
      const float4 hv = *(const float4*)(dh + (size_t)(b0 + r) * 8192 +
                                         (size_t)pair * 32 + q * 4);
      *(float4*)&h_lds[r][q * 4] = hv;
    }
  }
  __syncthreads();

  // ---- compute: 8 rows per thread, d-quad each ----
  for (int it = 0; it < 8; ++it) {
    const int r = it * 32 + s;
    float4 acc = make_float4(0.f, 0.f, 0.f, 0.f);
#pragma unroll
    for (int q = 0; q < 8; ++q) {
      const float4 h4 = *(const float4*)&h_lds[r][q * 4];
      acc.x += wr[0][q].x * h4.x + wr[0][q].y * h4.y + wr[0][q].z * h4.z + wr[0][q].w * h4.w;
      acc.y += wr[1][q].x * h4.x + wr[1][q].y * h4.y + wr[1][q].z * h4.z + wr[1][q].w * h4.w;
      acc.z += wr[2][q].x * h4.x + wr[2][q].y * h4.y + wr[2][q].z * h4.z + wr[2][q].w * h4.w;
      acc.w += wr[3][q].x * h4.x + wr[3][q].y * h4.y + wr[3][q].z * h4.z + wr[3][q].w * h4.w;
    }
    const float4 hres = *(const float4*)&h_lds[r][g * 4];
    float4 o;
    o.x = tanh_fast(acc.x + cc.x) + hres.x;
    o.y = tanh_fast(acc.y + cc.y) + hres.y;
    o.z = tanh_fast(acc.z + cc.z) + hres.z;
    o.w = tanh_fast(acc.w + cc.w) + hres.w;
    *(float4*)(out + (size_t)(b0 + r) * 8192 + (size_t)pair * 32 + g * 4) = o;
  }
}

extern "C" void kernel_launch(void* const* d_in, const int* in_sizes, int n_in,
                              void* d_out, int out_size, void* d_ws, size_t ws_size,
                              hipStream_t stream) {
  const float* sh = (const float*)d_in[0];
  const float* dh = (const float*)d_in[1];
  const float* v  = (const float*)d_in[2];
  const float* bv = (const float*)d_in[3];
  const float* w  = (const float*)d_in[4];
  const float* c  = (const float*)d_in[5];
  float* out = (float*)d_out;
  (void)d_ws; (void)ws_size;

  float* out_s = out;               // (B,N,256)   = 16,777,216 f
  float* out_d = out + 16777216;    // (B,N,N,32)  = 33,554,432 f

  // Scratch inside double-out region (k_double overwrites it last):
  float* gup  = out_d;                       // 1,048,576 f
  float* gdn  = out_d + 1048576;             // 1,048,576 f
  float* dgup = out_d + 2097152;             // 2,097,152 f
  float* dgdn = out_d + 4194304;             // 2,097,152 f
  u16*  vspl  = (u16*)(out_d + 6291456);     // 16*26*16384 u16 = 13.6 MB

  k_pool_g <<<4096, 256, 0, stream>>>(sh, gup, gdn);
  k_pool_dg<<<8192, 256, 0, stream>>>(dh, dgup, dgdn);
  k_vsplit <<< 416, 256, 0, stream>>>(v, vspl);
  k_single <<< 512, 256, 0, stream>>>(sh, vspl, bv, gup, gdn, dgup, dgdn, out_s);
  k_double <<<4096, 256, 0, stream>>>(dh, w, c, out_d);
}